// Round 1
// baseline (245.141 us; speedup 1.0000x reference)
//
#include <hip/hip_runtime.h>
#include <cfloat>

#define LL 512
#define NB 128

constexpr float MAXT   = 86400.0f;
constexpr float MAXD   = 50000.0f;
constexpr float EARTH2 = 2.0f * 6367000.0f;           // 2 * EARTH
constexpr float D2R    = 0.017453292519943295f;        // pi/180
constexpr float EPSF   = 1e-12f;
constexpr float NEGV   = -1000000000.0f;

// Pass 1: per-row inverse L2 norms of t_matr / s_matr, row-min of r,
// per-batch max of r (atomic on float bits; r >= 0 so uint order == float order).
__global__ __launch_bounds__(256) void k_pass1(
    const float* __restrict__ t_s, const float* __restrict__ s_s,
    const int* __restrict__ val_len,
    float* __restrict__ w_itn, float* __restrict__ w_isn,
    float* __restrict__ w_rmin, unsigned int* __restrict__ w_rmax)
{
    const int row = blockIdx.x;
    const int b = row >> 9;
    const int i = row & (LL - 1);
    const int vl = val_len[b];
    if (i >= vl) return;                 // row contributes nothing (r==0 <= rmax init 0)
    const int n = i + 1;
    const int tid = threadIdx.x;

    __shared__ float dt_s[LL];
    __shared__ float ds_s[LL];
    __shared__ float red_a[4], red_b[4];

    const float* tb = t_s + b * LL;
    const float* sb = s_s + (size_t)b * LL * 2;

    const float t_i   = tb[i];
    const float lon_i = sb[2 * i]     * D2R;
    const float lat_i = sb[2 * i + 1] * D2R;
    const float cl_i  = cosf(lat_i);

    float sum_t = 0.0f, sum_s = 0.0f;
    for (int j = tid; j < n; j += 256) {
        float dt    = fminf(fabsf(t_i - tb[j]), MAXT);
        float lon_j = sb[2 * j]     * D2R;
        float lat_j = sb[2 * j + 1] * D2R;
        float sa = sinf((lat_j - lat_i) * 0.5f);
        float so = sinf((lon_j - lon_i) * 0.5f);
        float a  = sa * sa + cl_i * cosf(lat_j) * (so * so);
        float ds = fminf(EARTH2 * asinf(sqrtf(a)), MAXD);
        dt_s[j] = dt;
        ds_s[j] = ds;
        sum_t += dt * dt;
        sum_s += ds * ds;
    }
    for (int m = 32; m; m >>= 1) {
        sum_t += __shfl_xor(sum_t, m, 64);
        sum_s += __shfl_xor(sum_s, m, 64);
    }
    const int lane = tid & 63, wid = tid >> 6;
    if (lane == 0) { red_a[wid] = sum_t; red_b[wid] = sum_s; }
    __syncthreads();
    sum_t = red_a[0] + red_a[1] + red_a[2] + red_a[3];
    sum_s = red_b[0] + red_b[1] + red_b[2] + red_b[3];
    const float itn = 1.0f / fmaxf(sqrtf(sum_t), EPSF);
    const float isn = 1.0f / fmaxf(sqrtf(sum_s), EPSF);

    __syncthreads();  // red_a/red_b consumed by all; safe to reuse below
    float mn = FLT_MAX, mx = 0.0f;   // idle lanes are neutral (r >= 0)
    for (int j = tid; j < n; j += 256) {
        float rv = dt_s[j] * itn + ds_s[j] * isn;
        mn = fminf(mn, rv);
        mx = fmaxf(mx, rv);
    }
    for (int m = 32; m; m >>= 1) {
        mn = fminf(mn, __shfl_xor(mn, m, 64));
        mx = fmaxf(mx, __shfl_xor(mx, m, 64));
    }
    if (lane == 0) { red_a[wid] = mn; red_b[wid] = mx; }
    __syncthreads();
    if (tid == 0) {
        mn = fminf(fminf(red_a[0], red_a[1]), fminf(red_a[2], red_a[3]));
        mx = fmaxf(fmaxf(red_b[0], red_b[1]), fmaxf(red_b[2], red_b[3]));
        w_itn[row]  = itn;
        w_isn[row]  = isn;
        w_rmin[row] = mn;
        atomicMax(&w_rmax[b], __float_as_uint(mx));
    }
}

// Pass 2: recompute r per valid pair, softmax over the full row (masked
// positions contribute exp(-zmax) each, per the reference), write output.
__global__ __launch_bounds__(256) void k_pass2(
    const float* __restrict__ t_s, const float* __restrict__ s_s,
    const int* __restrict__ val_len,
    const float* __restrict__ w_itn, const float* __restrict__ w_isn,
    const float* __restrict__ w_rmin, const unsigned int* __restrict__ w_rmax,
    float* __restrict__ out)
{
    const int row = blockIdx.x;
    const int b = row >> 9;
    const int i = row & (LL - 1);
    const int tid = threadIdx.x;
    float* orow = out + (size_t)row * LL;
    const int vl = val_len[b];

    if (i >= vl) {  // fully masked row -> all -1e9
        float4 nv = make_float4(NEGV, NEGV, NEGV, NEGV);
        float4* o4 = reinterpret_cast<float4*>(orow);
        if (tid < LL / 4) o4[tid] = nv;
        return;
    }

    const int n = i + 1;
    __shared__ float e_s[LL];
    __shared__ float red_a[4];

    const float itn  = w_itn[row];
    const float isn  = w_isn[row];
    const float rmx  = __uint_as_float(w_rmax[b]);
    const float zmax = rmx - w_rmin[row];   // >= 0, also >= masked z (=0)

    const float* tb = t_s + b * LL;
    const float* sb = s_s + (size_t)b * LL * 2;
    const float t_i   = tb[i];
    const float lon_i = sb[2 * i]     * D2R;
    const float lat_i = sb[2 * i + 1] * D2R;
    const float cl_i  = cosf(lat_i);

    float sum = 0.0f;
    for (int j = tid; j < n; j += 256) {
        float dt    = fminf(fabsf(t_i - tb[j]), MAXT);
        float lon_j = sb[2 * j]     * D2R;
        float lat_j = sb[2 * j + 1] * D2R;
        float sa = sinf((lat_j - lat_i) * 0.5f);
        float so = sinf((lon_j - lon_i) * 0.5f);
        float a  = sa * sa + cl_i * cosf(lat_j) * (so * so);
        float ds = fminf(EARTH2 * asinf(sqrtf(a)), MAXD);
        float rv = dt * itn + ds * isn;
        float ev = expf((rmx - rv) - zmax);
        e_s[j] = ev;
        sum += ev;
    }
    for (int m = 32; m; m >>= 1) sum += __shfl_xor(sum, m, 64);
    const int lane = tid & 63, wid = tid >> 6;
    if (lane == 0) red_a[wid] = sum;
    __syncthreads();
    sum = red_a[0] + red_a[1] + red_a[2] + red_a[3];
    const float denom = sum + (float)(LL - n) * expf(-zmax);
    const float inv = 1.0f / denom;

    for (int j = tid; j < LL; j += 256) {
        orow[j] = (j < n) ? e_s[j] * inv : NEGV;
    }
}

extern "C" void kernel_launch(void* const* d_in, const int* in_sizes, int n_in,
                              void* d_out, int out_size, void* d_ws, size_t ws_size,
                              hipStream_t stream) {
    const float* t_s     = (const float*)d_in[0];
    const float* s_s     = (const float*)d_in[1];
    const int*   val_len = (const int*)d_in[2];
    float* out = (float*)d_out;

    float* ws = (float*)d_ws;
    unsigned int* w_rmax = (unsigned int*)ws;   // NB entries
    float* w_itn  = ws + NB;                    // NB*LL
    float* w_isn  = w_itn + NB * LL;            // NB*LL
    float* w_rmin = w_isn + NB * LL;            // NB*LL

    hipMemsetAsync(d_ws, 0, NB * sizeof(float), stream);  // zero rmax accumulators

    dim3 grid(NB * LL), blk(256);
    k_pass1<<<grid, blk, 0, stream>>>(t_s, s_s, val_len, w_itn, w_isn, w_rmin, w_rmax);
    k_pass2<<<grid, blk, 0, stream>>>(t_s, s_s, val_len, w_itn, w_isn, w_rmin, w_rmax, out);
}

// Round 2
// 193.882 us; speedup vs baseline: 1.2644x; 1.2644x over previous
//
#include <hip/hip_runtime.h>

#define LL 512
#define NB 128

constexpr float MAXT   = 86400.0f;
constexpr float MAXD   = 50000.0f;
constexpr float EARTH2 = 2.0f * 6367000.0f;           // 2 * EARTH
constexpr float D2R    = 0.017453292519943295f;        // pi/180
constexpr float EPSF   = 1e-12f;
constexpr float NEGV   = -1000000000.0f;

// Pass 0: per-point trig table (cos/sin of lat and lon in radians).
__global__ __launch_bounds__(256) void k_table(const float* __restrict__ s_s,
                                               float4* __restrict__ tab) {
    int idx = blockIdx.x * 256 + threadIdx.x;
    float lon = s_s[2 * idx]     * D2R;
    float lat = s_s[2 * idx + 1] * D2R;
    tab[idx] = make_float4(cosf(lat), sinf(lat), cosf(lon), sinf(lon));
}

// Pairwise (dt, ds) from the trig table — pure FMA/rcp/sqrt, no libcalls.
// haversine: a = sin^2(dlat/2) + cos(lat_i)cos(lat_j) sin^2(dlon/2)
// with sin^2(d/2) = sin^2(d) / (2(1+cos d)); sin/cos(d) via angle-difference.
// asin(x) ~ x(1 + a/6 + 3a^2/40): exact to ~1e-14 for x<=0.024; larger x
// clamps to MAXD anyway.
__device__ __forceinline__ float2 pair_dtds(float t_i, float4 pi,
                                            float t_j, float4 pj) {
    float dt = fminf(fabsf(t_i - t_j), MAXT);
    float p  = pi.x * pj.x;                            // cos_lat_i * cos_lat_j
    float c1 = fmaf(pi.y, pj.y, p);                    // cos(dlat)
    float s1 = fmaf(pi.y, pj.x, -pi.x * pj.y);         // sin(dlat)
    float h1 = s1 * s1 * __builtin_amdgcn_rcpf(fmaf(2.0f, c1, 2.0f));
    float c2 = fmaf(pi.w, pj.w, pi.z * pj.z);          // cos(dlon)
    float s2 = fmaf(pi.w, pj.z, -pi.z * pj.w);         // sin(dlon)
    float h2 = s2 * s2 * __builtin_amdgcn_rcpf(fmaf(2.0f, c2, 2.0f));
    float a  = fmaf(p, h2, h1);
    float x  = __builtin_amdgcn_sqrtf(a);
    float as = x * fmaf(a, fmaf(a, 0.075f, 0.16666667f), 1.0f);
    float ds = fminf(EARTH2 * as, MAXD);
    return make_float2(dt, ds);
}

// Pass 1: per-row inverse L2 norms + per-batch max of r (atomic on float
// bits; r >= 0 so uint order == float order). Pairs held in registers.
__global__ __launch_bounds__(256) void k_pass1(
    const float* __restrict__ t_s, const float4* __restrict__ tab,
    const int* __restrict__ val_len,
    float2* __restrict__ w_norm, unsigned int* __restrict__ w_rmax)
{
    const int row = blockIdx.x;
    const int b = row >> 9;
    const int i = row & (LL - 1);
    if (i >= val_len[b]) return;          // r == 0 rows can't raise rmax (>=0)
    const int n = i + 1;
    const int tid = threadIdx.x;

    const float*  tb = t_s + b * LL;
    const float4* pb = tab + b * LL;
    const float  t_i = tb[i];
    const float4 pi  = pb[i];

    float dt0 = 0.0f, ds0 = 0.0f, dt1 = 0.0f, ds1 = 0.0f;
    if (tid < n) { float2 v = pair_dtds(t_i, pi, tb[tid], pb[tid]); dt0 = v.x; ds0 = v.y; }
    const int j1 = tid + 256;
    if (j1 < n)  { float2 v = pair_dtds(t_i, pi, tb[j1],  pb[j1]);  dt1 = v.x; ds1 = v.y; }

    float st = fmaf(dt0, dt0, dt1 * dt1);
    float ss = fmaf(ds0, ds0, ds1 * ds1);
    #pragma unroll
    for (int m = 32; m; m >>= 1) {
        st += __shfl_xor(st, m, 64);
        ss += __shfl_xor(ss, m, 64);
    }
    __shared__ float ra[4], rb[4], rc[4];
    const int lane = tid & 63, wid = tid >> 6;
    if (lane == 0) { ra[wid] = st; rb[wid] = ss; }
    __syncthreads();
    st = ra[0] + ra[1] + ra[2] + ra[3];
    ss = rb[0] + rb[1] + rb[2] + rb[3];
    const float itn = __builtin_amdgcn_rcpf(fmaxf(__builtin_amdgcn_sqrtf(st), EPSF));
    const float isn = __builtin_amdgcn_rcpf(fmaxf(__builtin_amdgcn_sqrtf(ss), EPSF));

    const float r0 = fmaf(dt0, itn, ds0 * isn);
    const float r1 = fmaf(dt1, itn, ds1 * isn);
    float mx = fmaxf(r0, r1);
    #pragma unroll
    for (int m = 32; m; m >>= 1) mx = fmaxf(mx, __shfl_xor(mx, m, 64));
    if (lane == 0) rc[wid] = mx;
    __syncthreads();
    if (tid == 0) {
        mx = fmaxf(fmaxf(rc[0], rc[1]), fmaxf(rc[2], rc[3]));
        w_norm[row] = make_float2(itn, isn);
        atomicMax(&w_rmax[b], __float_as_uint(mx));
    }
}

// Pass 2: recompute r, softmax over the full row. r <= 2 (unit-norm rows),
// so exp(rmax - r) <= e^2 needs no stability shift; masked entries each
// contribute exp(0) = 1 to the denominator, added analytically.
__global__ __launch_bounds__(256) void k_pass2(
    const float* __restrict__ t_s, const float4* __restrict__ tab,
    const int* __restrict__ val_len,
    const float2* __restrict__ w_norm, const unsigned int* __restrict__ w_rmax,
    float* __restrict__ out)
{
    const int row = blockIdx.x;
    const int b = row >> 9;
    const int i = row & (LL - 1);
    const int tid = threadIdx.x;
    float* orow = out + (size_t)row * LL;

    if (i >= val_len[b]) {               // fully masked row -> all -1e9
        if (tid < LL / 4)
            reinterpret_cast<float4*>(orow)[tid] = make_float4(NEGV, NEGV, NEGV, NEGV);
        return;
    }
    const int n = i + 1;
    const float*  tb = t_s + b * LL;
    const float4* pb = tab + b * LL;
    const float  t_i = tb[i];
    const float4 pi  = pb[i];
    const float2 nn  = w_norm[row];
    const float  rmx = __uint_as_float(w_rmax[b]);

    float ev0 = 0.0f, ev1 = 0.0f;
    if (tid < n) {
        float2 v = pair_dtds(t_i, pi, tb[tid], pb[tid]);
        ev0 = __expf(rmx - fmaf(v.x, nn.x, v.y * nn.y));
    }
    const int j1 = tid + 256;
    if (j1 < n) {
        float2 v = pair_dtds(t_i, pi, tb[j1], pb[j1]);
        ev1 = __expf(rmx - fmaf(v.x, nn.x, v.y * nn.y));
    }
    float s = ev0 + ev1;
    #pragma unroll
    for (int m = 32; m; m >>= 1) s += __shfl_xor(s, m, 64);
    __shared__ float ra[4];
    const int lane = tid & 63, wid = tid >> 6;
    if (lane == 0) ra[wid] = s;
    __syncthreads();
    s = ra[0] + ra[1] + ra[2] + ra[3] + (float)(LL - n);
    const float inv = 1.0f / s;

    orow[tid] = (tid < n) ? ev0 * inv : NEGV;
    orow[j1]  = (j1 < n)  ? ev1 * inv : NEGV;
}

extern "C" void kernel_launch(void* const* d_in, const int* in_sizes, int n_in,
                              void* d_out, int out_size, void* d_ws, size_t ws_size,
                              hipStream_t stream) {
    const float* t_s     = (const float*)d_in[0];
    const float* s_s     = (const float*)d_in[1];
    const int*   val_len = (const int*)d_in[2];
    float* out = (float*)d_out;

    char* ws = (char*)d_ws;
    float4*       tab    = (float4*)ws;                                   // 1 MB
    float2*       w_norm = (float2*)(ws + (size_t)NB * LL * sizeof(float4));   // 512 KB
    unsigned int* w_rmax = (unsigned int*)(ws + (size_t)NB * LL * (sizeof(float4) + sizeof(float2)));

    hipMemsetAsync(w_rmax, 0, NB * sizeof(unsigned int), stream);

    k_table<<<NB * LL / 256, 256, 0, stream>>>(s_s, tab);
    k_pass1<<<NB * LL, 256, 0, stream>>>(t_s, tab, val_len, w_norm, w_rmax);
    k_pass2<<<NB * LL, 256, 0, stream>>>(t_s, tab, val_len, w_norm, w_rmax, out);
}

// Round 3
// 60.925 us; speedup vs baseline: 4.0237x; 3.1823x over previous
//
#include <hip/hip_runtime.h>

#define LL 512
#define NB 128

constexpr float MAXT   = 86400.0f;
constexpr float MAXD   = 50000.0f;
constexpr float EARTH2 = 2.0f * 6367000.0f;           // 2 * EARTH
constexpr float D2R    = 0.017453292519943295f;        // pi/180
constexpr float EPSF   = 1e-12f;
constexpr float NEGV   = -1000000000.0f;

__device__ __forceinline__ float wred_sum(float v) {
    #pragma unroll
    for (int m = 32; m; m >>= 1) v += __shfl_xor(v, m, 64);
    return v;
}
__device__ __forceinline__ float wred_max(float v) {
    #pragma unroll
    for (int m = 32; m; m >>= 1) v = fmaxf(v, __shfl_xor(v, m, 64));
    return v;
}

// Pass 0: per-point trig table (cos/sin of lat and lon in radians).
__global__ __launch_bounds__(256) void k_table(const float* __restrict__ s_s,
                                               float4* __restrict__ tab) {
    int idx = blockIdx.x * 256 + threadIdx.x;
    float lon = s_s[2 * idx]     * D2R;
    float lat = s_s[2 * idx + 1] * D2R;
    tab[idx] = make_float4(cosf(lat), sinf(lat), cosf(lon), sinf(lon));
}

// Pairwise (dt, ds) from the trig table — pure FMA/rcp/sqrt, no libcalls.
// haversine with sin^2(d/2) = sin^2(d)/(2(1+cos d)); asin via 2-term series
// (exact to ~1e-9 below the MAXD clamp threshold of x~0.004).
__device__ __forceinline__ float2 pair_dtds(float t_i, float4 pi,
                                            float t_j, float4 pj) {
    float dt = fminf(fabsf(t_i - t_j), MAXT);
    float p  = pi.x * pj.x;                            // cos_lat_i * cos_lat_j
    float c1 = fmaf(pi.y, pj.y, p);                    // cos(dlat)
    float s1 = fmaf(pi.y, pj.x, -pi.x * pj.y);         // sin(dlat)
    float h1 = s1 * s1 * __builtin_amdgcn_rcpf(fmaf(2.0f, c1, 2.0f));
    float c2 = fmaf(pi.w, pj.w, pi.z * pj.z);          // cos(dlon)
    float s2 = fmaf(pi.w, pj.z, -pi.z * pj.w);         // sin(dlon)
    float h2 = s2 * s2 * __builtin_amdgcn_rcpf(fmaf(2.0f, c2, 2.0f));
    float a  = fmaf(p, h2, h1);
    float x  = __builtin_amdgcn_sqrtf(a);
    float as = x * fmaf(a, fmaf(a, 0.075f, 0.16666667f), 1.0f);
    float ds = fminf(EARTH2 * as, MAXD);
    return make_float2(dt, ds);
}

// Pass 1: one wave per row. Per-row inverse L2 norms + row max of r.
// No LDS, no barriers, no atomics.
__global__ __launch_bounds__(256) void k_pass1(
    const float* __restrict__ t_s, const float4* __restrict__ tab,
    const int* __restrict__ val_len,
    float2* __restrict__ w_norm, float* __restrict__ w_rowmax)
{
    const int tid  = threadIdx.x;
    const int lane = tid & 63;
    const int row  = blockIdx.x * 4 + (tid >> 6);
    const int b = row >> 9;
    const int i = row & (LL - 1);
    if (i >= val_len[b]) {                 // invalid row: rowmax 0 (r >= 0)
        if (lane == 0) w_rowmax[row] = 0.0f;
        return;
    }
    const int n = i + 1;
    const float*  tb = t_s + b * LL;
    const float4* pb = tab + b * LL;
    const float  t_i = tb[i];
    const float4 pi  = pb[i];

    float dt[8], ds[8];
    float st = 0.0f, ss = 0.0f;
    #pragma unroll
    for (int h = 0; h < 2; ++h) {
        const int jbase = h * 256 + 4 * lane;
        #pragma unroll
        for (int c = 0; c < 4; ++c) {
            const int j = jbase + c;
            float dtv = 0.0f, dsv = 0.0f;
            if (j < n) {
                float2 v = pair_dtds(t_i, pi, tb[j], pb[j]);
                dtv = v.x; dsv = v.y;
            }
            dt[h * 4 + c] = dtv; ds[h * 4 + c] = dsv;
            st = fmaf(dtv, dtv, st);
            ss = fmaf(dsv, dsv, ss);
        }
    }
    st = wred_sum(st);
    ss = wred_sum(ss);
    const float itn = __builtin_amdgcn_rcpf(fmaxf(__builtin_amdgcn_sqrtf(st), EPSF));
    const float isn = __builtin_amdgcn_rcpf(fmaxf(__builtin_amdgcn_sqrtf(ss), EPSF));

    float mx = 0.0f;
    #pragma unroll
    for (int k = 0; k < 8; ++k) mx = fmaxf(mx, fmaf(dt[k], itn, ds[k] * isn));
    mx = wred_max(mx);
    if (lane == 0) {
        w_norm[row]   = make_float2(itn, isn);
        w_rowmax[row] = mx;
    }
}

// Reduce 512 row-maxes -> per-batch max. One block per batch.
__global__ __launch_bounds__(256) void k_rmax(const float* __restrict__ w_rowmax,
                                              float* __restrict__ w_rmax) {
    const int b = blockIdx.x, tid = threadIdx.x;
    const float* p = w_rowmax + b * LL;
    float v = fmaxf(p[tid], p[tid + 256]);
    v = wred_max(v);
    __shared__ float red[4];
    if ((tid & 63) == 0) red[tid >> 6] = v;
    __syncthreads();
    if (tid == 0)
        w_rmax[b] = fmaxf(fmaxf(red[0], red[1]), fmaxf(red[2], red[3]));
}

// Pass 2: one wave per row; recompute r, softmax, float4 stores.
// r <= 2 (unit-norm rows) so exp(rmax - r) <= e^2 needs no shift; masked
// entries each contribute exp(0) = 1 to the denominator, added analytically.
__global__ __launch_bounds__(256) void k_pass2(
    const float* __restrict__ t_s, const float4* __restrict__ tab,
    const int* __restrict__ val_len,
    const float2* __restrict__ w_norm, const float* __restrict__ w_rmax,
    float* __restrict__ out)
{
    const int tid  = threadIdx.x;
    const int lane = tid & 63;
    const int row  = blockIdx.x * 4 + (tid >> 6);
    const int b = row >> 9;
    const int i = row & (LL - 1);
    float4* o4 = reinterpret_cast<float4*>(out + (size_t)row * LL);

    if (i >= val_len[b]) {                 // fully masked row -> all -1e9
        const float4 nv = make_float4(NEGV, NEGV, NEGV, NEGV);
        o4[lane]      = nv;
        o4[lane + 64] = nv;
        return;
    }
    const int n = i + 1;
    const float*  tb = t_s + b * LL;
    const float4* pb = tab + b * LL;
    const float  t_i = tb[i];
    const float4 pi  = pb[i];
    const float2 nn  = w_norm[row];
    const float  rmx = w_rmax[b];

    float ev[8];
    float s = 0.0f;
    #pragma unroll
    for (int h = 0; h < 2; ++h) {
        const int jbase = h * 256 + 4 * lane;
        #pragma unroll
        for (int c = 0; c < 4; ++c) {
            const int j = jbase + c;
            float e = 0.0f;
            if (j < n) {
                float2 v = pair_dtds(t_i, pi, tb[j], pb[j]);
                e = __expf(rmx - fmaf(v.x, nn.x, v.y * nn.y));
            }
            ev[h * 4 + c] = e;
            s += e;
        }
    }
    s = wred_sum(s);
    const float inv = 1.0f / (s + (float)(LL - n));

    #pragma unroll
    for (int h = 0; h < 2; ++h) {
        const int jbase = h * 256 + 4 * lane;
        float4 o;
        o.x = (jbase     < n) ? ev[h * 4 + 0] * inv : NEGV;
        o.y = (jbase + 1 < n) ? ev[h * 4 + 1] * inv : NEGV;
        o.z = (jbase + 2 < n) ? ev[h * 4 + 2] * inv : NEGV;
        o.w = (jbase + 3 < n) ? ev[h * 4 + 3] * inv : NEGV;
        o4[lane + h * 64] = o;
    }
}

extern "C" void kernel_launch(void* const* d_in, const int* in_sizes, int n_in,
                              void* d_out, int out_size, void* d_ws, size_t ws_size,
                              hipStream_t stream) {
    const float* t_s     = (const float*)d_in[0];
    const float* s_s     = (const float*)d_in[1];
    const int*   val_len = (const int*)d_in[2];
    float* out = (float*)d_out;

    char* ws = (char*)d_ws;
    float4* tab      = (float4*)ws;                                  // 1 MB
    float2* w_norm   = (float2*)(ws + (size_t)NB * LL * 16);         // 512 KB
    float*  w_rowmax = (float*) (ws + (size_t)NB * LL * 24);         // 256 KB
    float*  w_rmax   = (float*) (ws + (size_t)NB * LL * 28);         // 512 B

    k_table<<<NB * LL / 256, 256, 0, stream>>>(s_s, tab);
    k_pass1<<<NB * LL / 4, 256, 0, stream>>>(t_s, tab, val_len, w_norm, w_rowmax);
    k_rmax <<<NB, 256, 0, stream>>>(w_rowmax, w_rmax);
    k_pass2<<<NB * LL / 4, 256, 0, stream>>>(t_s, tab, val_len, w_norm, w_rmax, out);
}

// Round 4
// 52.020 us; speedup vs baseline: 4.7124x; 1.1712x over previous
//
#include <hip/hip_runtime.h>

#define LL 512
#define NB 128

constexpr float MAXT   = 86400.0f;
constexpr float MAXD   = 50000.0f;
constexpr float EARTH2 = 2.0f * 6367000.0f;           // 2 * EARTH
constexpr float D2R    = 0.017453292519943295f;        // pi/180
constexpr float EPSF   = 1e-12f;
constexpr float NEGV   = -1000000000.0f;

__device__ __forceinline__ float wred_sum(float v) {
    #pragma unroll
    for (int m = 32; m; m >>= 1) v += __shfl_xor(v, m, 64);
    return v;
}
__device__ __forceinline__ float wred_max(float v) {
    #pragma unroll
    for (int m = 32; m; m >>= 1) v = fmaxf(v, __shfl_xor(v, m, 64));
    return v;
}

// Pass 0: per-point trig table (cos/sin of lat and lon in radians).
__global__ __launch_bounds__(256) void k_table(const float* __restrict__ s_s,
                                               float4* __restrict__ tab) {
    int idx = blockIdx.x * 256 + threadIdx.x;
    float lon = s_s[2 * idx]     * D2R;
    float lat = s_s[2 * idx + 1] * D2R;
    tab[idx] = make_float4(cosf(lat), sinf(lat), cosf(lon), sinf(lon));
}

// Pairwise (dt, ds) from the trig table — pure FMA/rcp/sqrt, no libcalls.
// haversine with sin^2(d/2) = sin^2(d)/(2(1+cos d)); asin via 2-term series
// (exact to ~1e-9 below the MAXD clamp threshold).
__device__ __forceinline__ float2 pair_dtds(float t_i, float4 pi,
                                            float t_j, float4 pj) {
    float dt = fminf(fabsf(t_i - t_j), MAXT);
    float p  = pi.x * pj.x;                            // cos_lat_i * cos_lat_j
    float c1 = fmaf(pi.y, pj.y, p);                    // cos(dlat)
    float s1 = fmaf(pi.y, pj.x, -pi.x * pj.y);         // sin(dlat)
    float h1 = s1 * s1 * __builtin_amdgcn_rcpf(fmaf(2.0f, c1, 2.0f));
    float c2 = fmaf(pi.w, pj.w, pi.z * pj.z);          // cos(dlon)
    float s2 = fmaf(pi.w, pj.z, -pi.z * pj.w);         // sin(dlon)
    float h2 = s2 * s2 * __builtin_amdgcn_rcpf(fmaf(2.0f, c2, 2.0f));
    float a  = fmaf(p, h2, h1);
    float x  = __builtin_amdgcn_sqrtf(a);
    float as = x * fmaf(a, fmaf(a, 0.075f, 0.16666667f), 1.0f);
    float ds = fminf(EARTH2 * as, MAXD);
    return make_float2(dt, ds);
}

// Pass 1: one wave per row; j = lane + 64k (coalesced), wave-uniform skip of
// empty 64-chunks. Per-row inverse L2 norms + row max of r. No LDS/barriers.
__global__ __launch_bounds__(256) void k_pass1(
    const float* __restrict__ t_s, const float4* __restrict__ tab,
    const int* __restrict__ val_len,
    float2* __restrict__ w_norm, float* __restrict__ w_rowmax)
{
    const int tid  = threadIdx.x;
    const int lane = tid & 63;
    const int row  = blockIdx.x * 4 + (tid >> 6);
    const int b = row >> 9;
    const int i = row & (LL - 1);
    if (i >= val_len[b]) {                 // invalid row: rowmax 0 (r >= 0)
        if (lane == 0) w_rowmax[row] = 0.0f;
        return;
    }
    const int n = i + 1;
    const float*  tb = t_s + b * LL;
    const float4* pb = tab + b * LL;
    const float  t_i = tb[i];
    const float4 pi  = pb[i];

    float dt[8], ds[8];
    float st = 0.0f, ss = 0.0f;
    #pragma unroll
    for (int k = 0; k < 8; ++k) {
        dt[k] = 0.0f; ds[k] = 0.0f;
        if ((k << 6) < n) {                // wave-uniform chunk guard
            const int j = lane + (k << 6);
            if (j < n) {
                float2 v = pair_dtds(t_i, pi, tb[j], pb[j]);
                dt[k] = v.x; ds[k] = v.y;
                st = fmaf(v.x, v.x, st);
                ss = fmaf(v.y, v.y, ss);
            }
        }
    }
    st = wred_sum(st);
    ss = wred_sum(ss);
    const float itn = __builtin_amdgcn_rcpf(fmaxf(__builtin_amdgcn_sqrtf(st), EPSF));
    const float isn = __builtin_amdgcn_rcpf(fmaxf(__builtin_amdgcn_sqrtf(ss), EPSF));

    float mx = 0.0f;
    #pragma unroll
    for (int k = 0; k < 8; ++k) mx = fmaxf(mx, fmaf(dt[k], itn, ds[k] * isn));
    mx = wred_max(mx);
    if (lane == 0) {
        w_norm[row]   = make_float2(itn, isn);
        w_rowmax[row] = mx;
    }
}

// Pass 2: one wave per row; fused per-batch max reduce (8 L2-resident loads),
// recompute r, softmax, coalesced stores. r <= 2 (unit-norm rows) so
// exp(rmax - r) <= e^2 needs no shift; masked entries each contribute
// exp(0) = 1 to the denominator, added analytically.
__global__ __launch_bounds__(256) void k_pass2(
    const float* __restrict__ t_s, const float4* __restrict__ tab,
    const int* __restrict__ val_len,
    const float2* __restrict__ w_norm, const float* __restrict__ w_rowmax,
    float* __restrict__ out)
{
    const int tid  = threadIdx.x;
    const int lane = tid & 63;
    const int row  = blockIdx.x * 4 + (tid >> 6);
    const int b = row >> 9;
    const int i = row & (LL - 1);
    float* orow = out + (size_t)row * LL;

    if (i >= val_len[b]) {                 // fully masked row -> all -1e9
        float4* o4 = reinterpret_cast<float4*>(orow);
        const float4 nv = make_float4(NEGV, NEGV, NEGV, NEGV);
        o4[lane]      = nv;
        o4[lane + 64] = nv;
        return;
    }
    const int n = i + 1;

    // per-batch max of r (rowmax array is L2-resident; wave max-reduce)
    const float* rm = w_rowmax + (b << 9);
    float bm = fmaxf(rm[lane], rm[lane + 64]);
    #pragma unroll
    for (int k = 2; k < 8; ++k) bm = fmaxf(bm, rm[lane + (k << 6)]);
    const float rmx = wred_max(bm);

    const float*  tb = t_s + b * LL;
    const float4* pb = tab + b * LL;
    const float  t_i = tb[i];
    const float4 pi  = pb[i];
    const float2 nn  = w_norm[row];

    float ev[8];
    float s = 0.0f;
    #pragma unroll
    for (int k = 0; k < 8; ++k) {
        ev[k] = 0.0f;
        if ((k << 6) < n) {                // wave-uniform chunk guard
            const int j = lane + (k << 6);
            if (j < n) {
                float2 v = pair_dtds(t_i, pi, tb[j], pb[j]);
                float e = __expf(rmx - fmaf(v.x, nn.x, v.y * nn.y));
                ev[k] = e;
                s += e;
            }
        }
    }
    s = wred_sum(s);
    const float inv = 1.0f / (s + (float)(LL - n));

    #pragma unroll
    for (int k = 0; k < 8; ++k) {
        const int j = lane + (k << 6);
        orow[j] = (j < n) ? ev[k] * inv : NEGV;
    }
}

extern "C" void kernel_launch(void* const* d_in, const int* in_sizes, int n_in,
                              void* d_out, int out_size, void* d_ws, size_t ws_size,
                              hipStream_t stream) {
    const float* t_s     = (const float*)d_in[0];
    const float* s_s     = (const float*)d_in[1];
    const int*   val_len = (const int*)d_in[2];
    float* out = (float*)d_out;

    char* ws = (char*)d_ws;
    float4* tab      = (float4*)ws;                                  // 1 MB
    float2* w_norm   = (float2*)(ws + (size_t)NB * LL * 16);         // 512 KB
    float*  w_rowmax = (float*) (ws + (size_t)NB * LL * 24);         // 256 KB

    k_table<<<NB * LL / 256, 256, 0, stream>>>(s_s, tab);
    k_pass1<<<NB * LL / 4, 256, 0, stream>>>(t_s, tab, val_len, w_norm, w_rowmax);
    k_pass2<<<NB * LL / 4, 256, 0, stream>>>(t_s, tab, val_len, w_norm, w_rowmax, out);
}